// Round 1
// baseline (384.931 us; speedup 1.0000x reference)
//
#include <hip/hip_runtime.h>
#include <math.h>

constexpr int K = 512;
constexpr int D = 64;
constexpr int NB = 32;
constexpr int HW = 64 * 64;                     // 4096
constexpr int NPIX = NB * HW;                   // 131072
constexpr long long NELEM = (long long)NPIX * D; // 8388608
constexpr float BETA = 0.25f;
constexpr int TK = 128;                         // codes per LDS chunk

// ws layout: [0] float sse ; [1..512] uint counts ; [513..1024] float ee

__global__ void ee_kernel(const float* __restrict__ E, float* __restrict__ ee) {
    int k = blockIdx.x * blockDim.x + threadIdx.x;
    if (k < K) {
        const float* r = E + k * D;
        float a = 0.f;
#pragma unroll
        for (int d = 0; d < D; ++d) a = fmaf(r[d], r[d], a);
        ee[k] = a;
    }
}

__global__ __launch_bounds__(256) void vq_main(
    const float* __restrict__ z, const float* __restrict__ E,
    const float* __restrict__ ee, float* __restrict__ out,
    float* __restrict__ sse_acc, unsigned int* __restrict__ counts) {
    __shared__ float4 se[TK * (D / 4)];
    __shared__ float s_ee[TK];
    __shared__ unsigned int hcnt[K];

    const int tid = threadIdx.x;
    const int p = blockIdx.x * 256 + tid;
    const int b = p >> 12;          // 4096 pixels per batch image
    const int s = p & (HW - 1);

    for (int i = tid; i < K; i += 256) hcnt[i] = 0;

    // Load this pixel's z vector (coalesced across lanes for each d)
    const float* zp = z + (size_t)b * D * HW + s;
    float zr[D];
#pragma unroll
    for (int d = 0; d < D; ++d) zr[d] = zp[(size_t)d * HW];

    float best = 3.4e38f;
    int bestk = 0;

    for (int k0 = 0; k0 < K; k0 += TK) {
        __syncthreads();  // also covers hcnt init on first iter
        const float4* Ev = (const float4*)E + k0 * (D / 4);
        for (int i = tid; i < TK * (D / 4); i += 256) se[i] = Ev[i];
        for (int i = tid; i < TK; i += 256) s_ee[i] = ee[k0 + i];
        __syncthreads();

#pragma unroll 2
        for (int kk = 0; kk < TK; ++kk) {
            float dota = 0.f, dotb = 0.f;
            const float4* er = se + kk * (D / 4);
#pragma unroll
            for (int j = 0; j < D / 8; ++j) {
                float4 ea = er[j];
                float4 eb = er[j + D / 8];
                dota = fmaf(zr[4 * j + 0], ea.x, dota);
                dota = fmaf(zr[4 * j + 1], ea.y, dota);
                dota = fmaf(zr[4 * j + 2], ea.z, dota);
                dota = fmaf(zr[4 * j + 3], ea.w, dota);
                int d2 = 4 * j + D / 2;
                dotb = fmaf(zr[d2 + 0], eb.x, dotb);
                dotb = fmaf(zr[d2 + 1], eb.y, dotb);
                dotb = fmaf(zr[d2 + 2], eb.z, dotb);
                dotb = fmaf(zr[d2 + 3], eb.w, dotb);
            }
            float score = fmaf(-2.f, dota + dotb, s_ee[kk]);
            if (score < best) { best = score; bestk = k0 + kk; }
        }
    }

    // histogram (LDS first, flush at the end)
    atomicAdd(&hcnt[bestk], 1u);

    // gather winning code, write z_q (NCHW, coalesced per-d), accumulate SSE
    const float4* eq = (const float4*)(E + bestk * D);
    float lsse = 0.f;
    float* op = out + 1 + (size_t)b * D * HW + s;
#pragma unroll
    for (int j = 0; j < D / 4; ++j) {
        float4 e4 = eq[j];
        op[(size_t)(4 * j + 0) * HW] = e4.x;
        op[(size_t)(4 * j + 1) * HW] = e4.y;
        op[(size_t)(4 * j + 2) * HW] = e4.z;
        op[(size_t)(4 * j + 3) * HW] = e4.w;
        float d0 = e4.x - zr[4 * j + 0]; lsse = fmaf(d0, d0, lsse);
        float d1 = e4.y - zr[4 * j + 1]; lsse = fmaf(d1, d1, lsse);
        float d2 = e4.z - zr[4 * j + 2]; lsse = fmaf(d2, d2, lsse);
        float d3 = e4.w - zr[4 * j + 3]; lsse = fmaf(d3, d3, lsse);
    }

    // wave-level SSE reduction, one atomic per wave
#pragma unroll
    for (int off = 32; off > 0; off >>= 1) lsse += __shfl_down(lsse, off, 64);
    if ((tid & 63) == 0) atomicAdd(sse_acc, lsse);

    __syncthreads();  // all hcnt updates done
    for (int i = tid; i < K; i += 256) {
        unsigned int c = hcnt[i];
        if (c) atomicAdd(&counts[i], c);
    }
}

__global__ void finalize_kernel(const float* __restrict__ sse,
                                const unsigned int* __restrict__ counts,
                                float* __restrict__ out, int out_size) {
    __shared__ float red[8];
    int k = threadIdx.x;  // 512 threads
    float c = (float)counts[k];
    float p = c / (float)NPIX + 1e-10f;
    float t = p * logf(p);
#pragma unroll
    for (int off = 32; off > 0; off >>= 1) t += __shfl_down(t, off, 64);
    if ((k & 63) == 0) red[k >> 6] = t;
    __syncthreads();
    if (k == 0) {
        float tot = 0.f;
        for (int i = 0; i < 8; ++i) tot += red[i];
        out[out_size - 1] = expf(-tot);                     // perplexity
        out[0] = (1.f + BETA) * sse[0] / (float)NELEM;      // loss
    }
}

extern "C" void kernel_launch(void* const* d_in, const int* in_sizes, int n_in,
                              void* d_out, int out_size, void* d_ws, size_t ws_size,
                              hipStream_t stream) {
    const float* z = (const float*)d_in[0];
    const float* E = (const float*)d_in[1];
    float* out = (float*)d_out;

    float* sse = (float*)d_ws;
    unsigned int* counts = (unsigned int*)d_ws + 1;
    float* ee = (float*)d_ws + 1 + K;

    hipMemsetAsync(d_ws, 0, (1 + K) * sizeof(float), stream);
    ee_kernel<<<1, K, 0, stream>>>(E, ee);
    vq_main<<<NPIX / 256, 256, 0, stream>>>(z, E, ee, out, sse, counts);
    finalize_kernel<<<1, K, 0, stream>>>(sse, counts, out, out_size);
}

// Round 2
// 190.692 us; speedup vs baseline: 2.0186x; 2.0186x over previous
//
#include <hip/hip_runtime.h>
#include <math.h>

constexpr int K = 512;
constexpr int D = 64;
constexpr int NB = 32;
constexpr int HW = 64 * 64;                      // 4096
constexpr int NPIX = NB * HW;                    // 131072
constexpr long long NELEM = (long long)NPIX * D; // 8388608
constexpr float BETA = 0.25f;

typedef __attribute__((ext_vector_type(8))) short short8;
typedef __attribute__((ext_vector_type(16))) float f32x16;

// ws layout (floats): [0] sse, [1..3] pad, [4..515] counts(uint),
// [516..1027] ee, then ebhi (32768 ushort), eblo (32768 ushort)

__device__ inline unsigned short bf16rne(float x) {
    unsigned u = __float_as_uint(x);
    unsigned r = (u + 0x7FFFu + ((u >> 16) & 1u)) >> 16;
    return (unsigned short)r;
}

// Scatter -2*E into MFMA B-fragment order (bf16 hi + lo), compute ee = sum E^2 (fp32 exact).
// B-frag for tile t (32 cols), kstep ks: lane reads 16B at (t*4+ks)*512 + lane*8 shorts.
// Element E[n][k]: tile=n>>5, ks=k>>4, half=(k>>3)&1, idx=((n>>5)*4+(k>>4))*512+((k>>3)&1)*256+(n&31)*8+(k&7)
__global__ void prep_kernel(const float* __restrict__ E, float* __restrict__ ee,
                            unsigned short* __restrict__ ebhi, unsigned short* __restrict__ eblo) {
    int n = blockIdx.x * blockDim.x + threadIdx.x;
    if (n >= K) return;
    const float* row = E + n * D;
    float acc = 0.f;
#pragma unroll
    for (int k = 0; k < D; ++k) {
        float v = row[k];
        acc = fmaf(v, v, acc);
        float m2 = -2.f * v;
        unsigned short hi = bf16rne(m2);
        float hif = __uint_as_float((unsigned)hi << 16);
        unsigned short lo = bf16rne(m2 - hif);
        int idx = ((n >> 5) * 4 + (k >> 4)) * 512 + ((k >> 3) & 1) * 256 + (n & 31) * 8 + (k & 7);
        ebhi[idx] = hi;
        eblo[idx] = lo;
    }
    ee[n] = acc;
}

__global__ __launch_bounds__(256) void vq_mfma(
    const float* __restrict__ z, const float* __restrict__ E,
    const float* __restrict__ ee, const unsigned short* __restrict__ ebhi,
    const unsigned short* __restrict__ eblo, float* __restrict__ out,
    float* __restrict__ sse_acc, unsigned int* __restrict__ counts) {

    __shared__ float sval[128 * 33];
    __shared__ int scol[128 * 33];
    __shared__ int bks[128];
    __shared__ unsigned int hcnt[K];

    const int tid = threadIdx.x;
    const int wave = tid >> 6;
    const int lane = tid & 63;
    const int ln = lane & 31;
    const int half = lane >> 5;

    const int p0 = blockIdx.x * 128;
    const int b = p0 >> 12;
    const int s0 = p0 & (HW - 1);
    const int row_m = wave * 32 + ln;   // A-operand row (pixel within block)
    const int px = s0 + row_m;          // spatial index

    for (int i = tid; i < K; i += 256) hcnt[i] = 0;

    // ---- Load A (z) and convert to bf16 hi/lo fragments ----
    // A-frag (32x32x16): m = lane&31, k = kstep*16 + (lane>>5)*8 + j
    const float* zbase = z + (size_t)b * (D * HW) + px;
    float za[32];
#pragma unroll
    for (int ks = 0; ks < 4; ++ks)
#pragma unroll
        for (int j = 0; j < 8; ++j)
            za[ks * 8 + j] = zbase[(size_t)(ks * 16 + half * 8 + j) * HW];

    short8 ahi[4], alo[4];
#pragma unroll
    for (int ks = 0; ks < 4; ++ks) {
#pragma unroll
        for (int j = 0; j < 8; ++j) {
            float v = za[ks * 8 + j];
            unsigned short h = bf16rne(v);
            float hf = __uint_as_float((unsigned)h << 16);
            unsigned short l = bf16rne(v - hf);
            ahi[ks][j] = (short)h;
            alo[ks][j] = (short)l;
        }
    }

    float bestv[16];
    int bestc[16];
#pragma unroll
    for (int r = 0; r < 16; ++r) { bestv[r] = 3.4e38f; bestc[r] = 0; }

    // ---- Main loop: 16 col-tiles, processed in pairs ----
    for (int t2 = 0; t2 < 16; t2 += 2) {
        f32x16 acc0 = {0,0,0,0,0,0,0,0,0,0,0,0,0,0,0,0};
        f32x16 acc1 = {0,0,0,0,0,0,0,0,0,0,0,0,0,0,0,0};
#pragma unroll
        for (int ks = 0; ks < 4; ++ks) {
            int o0 = (t2 * 4 + ks) * 512 + lane * 8;
            int o1 = ((t2 + 1) * 4 + ks) * 512 + lane * 8;
            short8 b0h = *(const short8*)(ebhi + o0);
            short8 b0l = *(const short8*)(eblo + o0);
            short8 b1h = *(const short8*)(ebhi + o1);
            short8 b1l = *(const short8*)(eblo + o1);
            acc0 = __builtin_amdgcn_mfma_f32_32x32x16_bf16(ahi[ks], b0h, acc0, 0, 0, 0);
            acc1 = __builtin_amdgcn_mfma_f32_32x32x16_bf16(ahi[ks], b1h, acc1, 0, 0, 0);
            acc0 = __builtin_amdgcn_mfma_f32_32x32x16_bf16(alo[ks], b0h, acc0, 0, 0, 0);
            acc1 = __builtin_amdgcn_mfma_f32_32x32x16_bf16(alo[ks], b1h, acc1, 0, 0, 0);
            acc0 = __builtin_amdgcn_mfma_f32_32x32x16_bf16(ahi[ks], b0l, acc0, 0, 0, 0);
            acc1 = __builtin_amdgcn_mfma_f32_32x32x16_bf16(ahi[ks], b1l, acc1, 0, 0, 0);
        }
        float ee0 = ee[t2 * 32 + ln];
        float ee1 = ee[(t2 + 1) * 32 + ln];
        int c0 = t2 * 32 + ln;
        int c1 = (t2 + 1) * 32 + ln;
#pragma unroll
        for (int r = 0; r < 16; ++r) {
            float d0 = acc0[r] + ee0;
            float d1 = acc1[r] + ee1;
            if (d0 < bestv[r]) { bestv[r] = d0; bestc[r] = c0; }
            if (d1 < bestv[r]) { bestv[r] = d1; bestc[r] = c1; }
        }
    }

    // ---- Dump per-lane bests to LDS: row -> 32 col-candidates ----
    // C/D layout: col = lane&31, row = (reg&3) + 8*(reg>>2) + 4*(lane>>5)
#pragma unroll
    for (int r = 0; r < 16; ++r) {
        int rl = (r & 3) + 8 * (r >> 2) + 4 * half;
        int rg = wave * 32 + rl;
        sval[rg * 33 + ln] = bestv[r];
        scol[rg * 33 + ln] = bestc[r];
    }
    __syncthreads();

    // ---- Per-row argmin scan (first-min tie-break on global col) ----
    if (tid < 128) {
        float bv = 3.4e38f;
        int bc = 0;
#pragma unroll
        for (int c = 0; c < 32; ++c) {
            float v = sval[tid * 33 + c];
            int cc = scol[tid * 33 + c];
            if (v < bv || (v == bv && cc < bc)) { bv = v; bc = cc; }
        }
        bks[tid] = bc;
        atomicAdd(&hcnt[bc], 1u);
    }
    __syncthreads();

    // ---- Epilogue: gather exact codebook row, write z_q, accumulate SSE ----
    int bk = bks[row_m];
    const float* Eq = E + bk * D;
    float* outp = out + 1 + (size_t)b * (D * HW) + px;
    float lsse = 0.f;
#pragma unroll
    for (int ks = 0; ks < 4; ++ks) {
#pragma unroll
        for (int j = 0; j < 8; ++j) {
            int d = ks * 16 + half * 8 + j;
            float q = Eq[d];
            outp[(size_t)d * HW] = q;
            float zh = __uint_as_float((unsigned)(unsigned short)ahi[ks][j] << 16);
            float zl = __uint_as_float((unsigned)(unsigned short)alo[ks][j] << 16);
            float diff = q - (zh + zl);
            lsse = fmaf(diff, diff, lsse);
        }
    }
#pragma unroll
    for (int off = 32; off > 0; off >>= 1) lsse += __shfl_down(lsse, off, 64);
    if (lane == 0) atomicAdd(sse_acc, lsse);

    __syncthreads();
    for (int i = tid; i < K; i += 256) {
        unsigned int c = hcnt[i];
        if (c) atomicAdd(&counts[i], c);
    }
}

__global__ void finalize_kernel(const float* __restrict__ sse,
                                const unsigned int* __restrict__ counts,
                                float* __restrict__ out, int out_size) {
    __shared__ float red[8];
    int k = threadIdx.x;  // 512 threads
    float c = (float)counts[k];
    float p = c / (float)NPIX + 1e-10f;
    float t = p * logf(p);
#pragma unroll
    for (int off = 32; off > 0; off >>= 1) t += __shfl_down(t, off, 64);
    if ((k & 63) == 0) red[k >> 6] = t;
    __syncthreads();
    if (k == 0) {
        float tot = 0.f;
        for (int i = 0; i < 8; ++i) tot += red[i];
        out[out_size - 1] = expf(-tot);                 // perplexity
        out[0] = (1.f + BETA) * sse[0] / (float)NELEM;  // loss
    }
}

extern "C" void kernel_launch(void* const* d_in, const int* in_sizes, int n_in,
                              void* d_out, int out_size, void* d_ws, size_t ws_size,
                              hipStream_t stream) {
    const float* z = (const float*)d_in[0];
    const float* E = (const float*)d_in[1];
    float* out = (float*)d_out;

    float* wsf = (float*)d_ws;
    float* sse = wsf;                                  // [0]
    unsigned int* counts = (unsigned int*)(wsf + 4);   // 512
    float* ee = wsf + 4 + K;                           // 512
    unsigned short* ebhi = (unsigned short*)(wsf + 4 + 2 * K);  // 32768 ushort, 16B-aligned
    unsigned short* eblo = ebhi + K * D;

    hipMemsetAsync(d_ws, 0, (4 + K) * sizeof(float), stream);
    prep_kernel<<<2, 256, 0, stream>>>(E, ee, ebhi, eblo);
    vq_mfma<<<NPIX / 128, 256, 0, stream>>>(z, E, ee, ebhi, eblo, out, sse, counts);
    finalize_kernel<<<1, K, 0, stream>>>(sse, counts, out, out_size);
}

// Round 3
// 167.915 us; speedup vs baseline: 2.2924x; 1.1356x over previous
//
#include <hip/hip_runtime.h>
#include <math.h>

constexpr int K = 512;
constexpr int D = 64;
constexpr int HW = 64 * 64;                      // 4096
constexpr int NPIX = 131072;
constexpr long long NELEM = (long long)NPIX * D; // 8388608
constexpr float BETA = 0.25f;

typedef __attribute__((ext_vector_type(8))) short short8;
typedef __attribute__((ext_vector_type(16))) float f32x16;

__device__ inline unsigned short bf16rne(float x) {
    unsigned u = __float_as_uint(x);
    unsigned r = (u + 0x7FFFu + ((u >> 16) & 1u)) >> 16;
    return (unsigned short)r;
}

__device__ inline void async_cp16(const void* g, void* l) {
    __builtin_amdgcn_global_load_lds(
        (const __attribute__((address_space(1))) void*)g,
        (__attribute__((address_space(3))) void*)l, 16, 0, 0);
}

// One wave per codebook row. E[n][k] -> bf16 hi/lo of -2E in MFMA-B frag order,
// plus exact fp32 ee[n] = ||E_n||^2 via wave reduction.
__global__ __launch_bounds__(256) void prep_kernel(
    const float* __restrict__ E, float* __restrict__ ee,
    unsigned short* __restrict__ ebhi, unsigned short* __restrict__ eblo) {
    int gid = blockIdx.x * 256 + threadIdx.x;   // 0..32767
    int n = gid >> 6, k = gid & 63;
    float v = E[gid];
    float a = v * v;
#pragma unroll
    for (int off = 32; off > 0; off >>= 1) a += __shfl_down(a, off, 64);
    if ((threadIdx.x & 63) == 0) ee[n] = a;
    float m2 = -2.f * v;
    unsigned short hi = bf16rne(m2);
    unsigned short lo = bf16rne(m2 - __uint_as_float((unsigned)hi << 16));
    int idx = ((n >> 5) * 4 + (k >> 4)) * 512 + ((k >> 3) & 1) * 256 + (n & 31) * 8 + (k & 7);
    ebhi[idx] = hi;
    eblo[idx] = lo;
}

__global__ __launch_bounds__(256, 2) void vq_mfma(
    const float* __restrict__ z, const float* __restrict__ E,
    const float* __restrict__ ee, const unsigned short* __restrict__ ebhi,
    const unsigned short* __restrict__ eblo, float* __restrict__ out,
    float* __restrict__ sse_acc, unsigned int* __restrict__ counts) {

    __shared__ __align__(16) unsigned short sbh[2][2048];  // 4KB per buf (hi)
    __shared__ __align__(16) unsigned short sbl[2][2048];  // 4KB per buf (lo)
    __shared__ int bks[256];
    __shared__ unsigned int hcnt[K];

    const int tid = threadIdx.x;
    const int wave = tid >> 6;
    const int lane = tid & 63;
    const int ln = lane & 31;
    const int half = lane >> 5;

    const int p0 = blockIdx.x * 256;        // 256 pixels per block (one image: 4096 % 256 == 0)
    const int b = p0 >> 12;
    const int s0 = p0 & (HW - 1);
    const int base = s0 + wave * 64;        // this wave's 64 pixels: rows base..base+63

    hcnt[tid] = 0; hcnt[tid + 256] = 0;

    // prefetch B tile 0 into buffer 0 (hi+lo): block-wide contiguous copy
    async_cp16(ebhi + tid * 8, &sbh[0][wave * 512]);
    async_cp16(eblo + tid * 8, &sbl[0][wave * 512]);

    // ---- Load A (z) for 2 row-tiles, split to bf16 hi/lo ----
    // A-frag 32x32x16: m = lane&31, k = ks*16 + (lane>>5)*8 + j
    const float* zb = z + (size_t)b * (D * HW) + base;
    short8 ahi0[4], alo0[4], ahi1[4], alo1[4];
#pragma unroll
    for (int ks = 0; ks < 4; ++ks) {
#pragma unroll
        for (int j = 0; j < 8; ++j) {
            size_t doff = (size_t)(ks * 16 + half * 8 + j) * HW;
            float v0 = zb[doff + ln];
            float v1 = zb[doff + 32 + ln];
            unsigned short h0 = bf16rne(v0);
            unsigned short l0 = bf16rne(v0 - __uint_as_float((unsigned)h0 << 16));
            unsigned short h1 = bf16rne(v1);
            unsigned short l1 = bf16rne(v1 - __uint_as_float((unsigned)h1 << 16));
            ahi0[ks][j] = (short)h0; alo0[ks][j] = (short)l0;
            ahi1[ks][j] = (short)h1; alo1[ks][j] = (short)l1;
        }
    }

    float eet[16];
#pragma unroll
    for (int t = 0; t < 16; ++t) eet[t] = ee[t * 32 + ln];

    float bestp0[16], bestp1[16];
#pragma unroll
    for (int r = 0; r < 16; ++r) {
        bestp0[r] = __uint_as_float(0x7F800000u);
        bestp1[r] = __uint_as_float(0x7F800000u);
    }

    __syncthreads();

    int buf = 0;
    for (int t = 0; t < 16; ++t) {
        if (t < 15) {  // prefetch next tile; barrier drain is covered by this tile's MFMAs
            async_cp16(ebhi + (t + 1) * 2048 + tid * 8, &sbh[buf ^ 1][wave * 512]);
            async_cp16(eblo + (t + 1) * 2048 + tid * 8, &sbl[buf ^ 1][wave * 512]);
        }
        short8 vbh[4], vbl[4];
#pragma unroll
        for (int ks = 0; ks < 4; ++ks) {
            vbh[ks] = *(const short8*)&sbh[buf][ks * 512 + lane * 8];
            vbl[ks] = *(const short8*)&sbl[buf][ks * 512 + lane * 8];
        }
        f32x16 acc0 = {0,0,0,0,0,0,0,0,0,0,0,0,0,0,0,0};
        f32x16 acc1 = {0,0,0,0,0,0,0,0,0,0,0,0,0,0,0,0};
#pragma unroll
        for (int ks = 0; ks < 4; ++ks) {
            acc0 = __builtin_amdgcn_mfma_f32_32x32x16_bf16(ahi0[ks], vbh[ks], acc0, 0, 0, 0);
            acc1 = __builtin_amdgcn_mfma_f32_32x32x16_bf16(ahi1[ks], vbh[ks], acc1, 0, 0, 0);
            acc0 = __builtin_amdgcn_mfma_f32_32x32x16_bf16(alo0[ks], vbh[ks], acc0, 0, 0, 0);
            acc1 = __builtin_amdgcn_mfma_f32_32x32x16_bf16(alo1[ks], vbh[ks], acc1, 0, 0, 0);
            acc0 = __builtin_amdgcn_mfma_f32_32x32x16_bf16(ahi0[ks], vbl[ks], acc0, 0, 0, 0);
            acc1 = __builtin_amdgcn_mfma_f32_32x32x16_bf16(ahi1[ks], vbl[ks], acc1, 0, 0, 0);
        }
        float et = eet[t];
        unsigned cb = (unsigned)(t * 32 + ln);
#pragma unroll
        for (int r = 0; r < 16; ++r) {
            float d0 = acc0[r] + et;
            float d1 = acc1[r] + et;
            float k0 = __uint_as_float((__float_as_uint(d0) & ~0x1FFu) | cb);
            float k1 = __uint_as_float((__float_as_uint(d1) & ~0x1FFu) | cb);
            bestp0[r] = fminf(bestp0[r], k0);
            bestp1[r] = fminf(bestp1[r], k1);
        }
        __syncthreads();
        buf ^= 1;
    }

    // ---- Cross-lane argmin: butterfly min over the 32 cols (stays within half) ----
#pragma unroll
    for (int r = 0; r < 16; ++r) {
        float v0 = bestp0[r], v1 = bestp1[r];
#pragma unroll
        for (int m = 1; m < 32; m <<= 1) {
            v0 = fminf(v0, __shfl_xor(v0, m, 64));
            v1 = fminf(v1, __shfl_xor(v1, m, 64));
        }
        int row = (r & 3) + 8 * (r >> 2) + 4 * half;   // row within row-tile
        if (ln == r) {
            int c0 = (int)(__float_as_uint(v0) & 0x1FFu);
            int c1 = (int)(__float_as_uint(v1) & 0x1FFu);
            bks[wave * 64 + row] = c0;
            bks[wave * 64 + 32 + row] = c1;
            atomicAdd(&hcnt[c0], 1u);
            atomicAdd(&hcnt[c1], 1u);
        }
    }
    __syncthreads();

    // ---- Epilogue: gather exact codebook rows, write z_q, accumulate SSE ----
    int bk0 = bks[wave * 64 + ln];
    int bk1 = bks[wave * 64 + 32 + ln];
    float* outp = out + 1 + (size_t)b * (D * HW) + base;
    float lsse = 0.f;
#pragma unroll
    for (int ks = 0; ks < 4; ++ks) {
        const float4* q0p = (const float4*)(E + bk0 * D + ks * 16 + half * 8);
        const float4* q1p = (const float4*)(E + bk1 * D + ks * 16 + half * 8);
        float4 q0a = q0p[0], q0b = q0p[1];
        float4 q1a = q1p[0], q1b = q1p[1];
        float q0[8] = {q0a.x,q0a.y,q0a.z,q0a.w,q0b.x,q0b.y,q0b.z,q0b.w};
        float q1[8] = {q1a.x,q1a.y,q1a.z,q1a.w,q1b.x,q1b.y,q1b.z,q1b.w};
#pragma unroll
        for (int j = 0; j < 8; ++j) {
            size_t doff = (size_t)(ks * 16 + half * 8 + j) * HW;
            float z0 = __uint_as_float((unsigned)(unsigned short)ahi0[ks][j] << 16)
                     + __uint_as_float((unsigned)(unsigned short)alo0[ks][j] << 16);
            float z1 = __uint_as_float((unsigned)(unsigned short)ahi1[ks][j] << 16)
                     + __uint_as_float((unsigned)(unsigned short)alo1[ks][j] << 16);
            outp[doff + ln] = q0[j];
            outp[doff + 32 + ln] = q1[j];
            float e0 = q0[j] - z0; lsse = fmaf(e0, e0, lsse);
            float e1 = q1[j] - z1; lsse = fmaf(e1, e1, lsse);
        }
    }
#pragma unroll
    for (int off = 32; off > 0; off >>= 1) lsse += __shfl_down(lsse, off, 64);
    if (lane == 0) atomicAdd(sse_acc, lsse);

    __syncthreads();
    unsigned c0 = hcnt[tid], c1 = hcnt[tid + 256];
    if (c0) atomicAdd(&counts[tid], c0);
    if (c1) atomicAdd(&counts[tid + 256], c1);
}

__global__ void finalize_kernel(const float* __restrict__ sse,
                                const unsigned int* __restrict__ counts,
                                float* __restrict__ out, int out_size) {
    __shared__ float red[8];
    int k = threadIdx.x;  // 512 threads
    float c = (float)counts[k];
    float p = c / (float)NPIX + 1e-10f;
    float t = p * logf(p);
#pragma unroll
    for (int off = 32; off > 0; off >>= 1) t += __shfl_down(t, off, 64);
    if ((k & 63) == 0) red[k >> 6] = t;
    __syncthreads();
    if (k == 0) {
        float tot = 0.f;
        for (int i = 0; i < 8; ++i) tot += red[i];
        out[out_size - 1] = expf(-tot);                 // perplexity
        out[0] = (1.f + BETA) * sse[0] / (float)NELEM;  // loss
    }
}

extern "C" void kernel_launch(void* const* d_in, const int* in_sizes, int n_in,
                              void* d_out, int out_size, void* d_ws, size_t ws_size,
                              hipStream_t stream) {
    const float* z = (const float*)d_in[0];
    const float* E = (const float*)d_in[1];
    float* out = (float*)d_out;

    float* wsf = (float*)d_ws;
    float* sse = wsf;                                           // [0] (+pad to 16B)
    unsigned int* counts = (unsigned int*)(wsf + 4);            // 512 uints
    float* ee = wsf + 4 + K;                                    // 512 floats
    unsigned short* ebhi = (unsigned short*)(wsf + 4 + 2 * K);  // 32768 ushort (16B aligned)
    unsigned short* eblo = ebhi + K * D;                        // 32768 ushort

    hipMemsetAsync(d_ws, 0, (4 + K) * sizeof(float), stream);
    prep_kernel<<<128, 256, 0, stream>>>(E, ee, ebhi, eblo);
    vq_mfma<<<NPIX / 256, 256, 0, stream>>>(z, E, ee, ebhi, eblo, out, sse, counts);
    finalize_kernel<<<1, K, 0, stream>>>(sse, counts, out, out_size);
}